// Round 1
// baseline (177.133 us; speedup 1.0000x reference)
//
#include <hip/hip_runtime.h>

#define N_FEAT 32

// One thread per (edge, feature). 32 consecutive lanes = one edge row:
// - src/dst index loads are wave-broadcast (same address across the 32 lanes)
// - x[src] row read is a coalesced 128B transaction
// - atomicAdd scatter to out[dst] row (random, resolves in L2)
__global__ void mp_scatter_add(const float* __restrict__ x,
                               const int* __restrict__ src,
                               const int* __restrict__ dst,
                               float* __restrict__ out,
                               int n_edges) {
    long long tid = (long long)blockIdx.x * blockDim.x + threadIdx.x;
    long long total = (long long)n_edges * N_FEAT;
    if (tid >= total) return;
    int e = (int)(tid >> 5);   // edge index
    int f = (int)(tid & 31);   // feature index
    int s = src[e];
    int d = dst[e];
    float v = x[(long long)s * N_FEAT + f];
    atomicAdd(&out[(long long)d * N_FEAT + f], v);
}

__global__ void zero_out(float* __restrict__ out, int n) {
    int i = blockIdx.x * blockDim.x + threadIdx.x;
    if (i < n) out[i] = 0.0f;
}

extern "C" void kernel_launch(void* const* d_in, const int* in_sizes, int n_in,
                              void* d_out, int out_size, void* d_ws, size_t ws_size,
                              hipStream_t stream) {
    const float* x   = (const float*)d_in[0];
    const int*   ei  = (const int*)d_in[1];      // [2, E] flattened: row 0 = src, row 1 = dst
    float*       out = (float*)d_out;

    const int n_edges = in_sizes[1] / 2;
    const int* src = ei;
    const int* dst = ei + n_edges;

    // Zero the output (harness poisons d_out; we must produce exact sums).
    {
        int threads = 256;
        int blocks = (out_size + threads - 1) / threads;
        zero_out<<<blocks, threads, 0, stream>>>(out, out_size);
    }

    {
        long long total = (long long)n_edges * N_FEAT;
        int threads = 256;
        long long blocks = (total + threads - 1) / threads;
        mp_scatter_add<<<(int)blocks, threads, 0, stream>>>(x, src, dst, out, n_edges);
    }
}